// Round 5
// baseline (6114.564 us; speedup 1.0000x reference)
//
#include <hip/hip_runtime.h>

typedef __attribute__((ext_vector_type(8))) short short8;
typedef __attribute__((ext_vector_type(4))) float f32x4;

#define MFMA(a,b,c) __builtin_amdgcn_mfma_f32_16x16x32_bf16(a,b,c,0,0,0)

// Problem dims
#define S_LEN 128
#define IN_D  8
#define HID   512
#define NL    3
#define HSTR  536       // bf16 h row stride (shorts)
#define RING  3         // mailbox ring depth (race-free: reuse gated by 2 flag generations)

// ws layout (bytes)
#define OFF_WHH  0                       // [3][32][16][3][64][8] bf16 = 4,718,592
#define OFF_WIH  (4718592)               // [3][32][3][64][8] bf16    =   294,912
#define OFF_FLAG (4718592 + 294912)      // 256 * int                 =     1,024
#define OFF_XCHG (OFF_FLAG + 1024)       // 256 blk * 3 slot * 16 KB  = 12,582,912

__device__ __forceinline__ unsigned short f2bf(float f){
  unsigned u = __float_as_uint(f);
  u += 0x7FFFu + ((u >> 16) & 1u);     // round-to-nearest-even
  return (unsigned short)(u >> 16);
}

// Pack Whh [3][1536][512] f32 -> bf16 B-fragments, gate-interleaved per kk:
// dst chunk gid = (((l*32+nt)*16+kk)*3+g)*64+lane ; holds Whh[l][g*512+nt*16+(lane&15)][kk*32+(lane>>4)*8+j]
__global__ void prep_whh(const float* __restrict__ Whh, unsigned short* __restrict__ Wp){
  int gid = blockIdx.x * 256 + threadIdx.x;     // 294912 total
  int lane = gid & 63;
  int r = gid >> 6;
  int g  = r % 3;  r /= 3;
  int kk = r & 15; r >>= 4;
  int nt = r & 31;
  int l  = r >> 5;
  int n  = g * 512 + nt * 16 + (lane & 15);
  int k0 = kk * 32 + (lane >> 4) * 8;
  const float* src = Whh + ((size_t)l * 1536 + n) * 512 + k0;
  unsigned short t[8];
#pragma unroll
  for (int j = 0; j < 8; ++j) t[j] = f2bf(src[j]);
  uint4 v;
  v.x = t[0] | ((unsigned)t[1] << 16);
  v.y = t[2] | ((unsigned)t[3] << 16);
  v.z = t[4] | ((unsigned)t[5] << 16);
  v.w = t[6] | ((unsigned)t[7] << 16);
  *(uint4*)(Wp + (size_t)gid * 8) = v;
}

// Pack Wih [3][1536][8] -> zero-padded (K=8 of 32) B-fragments, gate-interleaved:
// dst chunk gid = ((l*32+nt)*3+g)*64+lane
__global__ void prep_wih(const float* __restrict__ Wih, unsigned short* __restrict__ Wip){
  int gid = blockIdx.x * 256 + threadIdx.x;     // 18432 total
  int lane = gid & 63;
  int r = gid >> 6;
  int g  = r % 3;  r /= 3;
  int nt = r & 31;
  int l  = r >> 5;
  unsigned short t[8] = {0,0,0,0,0,0,0,0};
  if ((lane >> 4) == 0){
    int n = g * 512 + nt * 16 + (lane & 15);
    const float* src = Wih + ((size_t)l * 1536 + n) * 8;
#pragma unroll
    for (int j = 0; j < 8; ++j) t[j] = f2bf(src[j]);
  }
  uint4 v;
  v.x = t[0] | ((unsigned)t[1] << 16);
  v.y = t[2] | ((unsigned)t[3] << 16);
  v.z = t[4] | ((unsigned)t[5] << 16);
  v.w = t[6] | ((unsigned)t[7] << 16);
  *(uint4*)(Wip + (size_t)gid * 8) = v;
}

// Main: 256 blocks x 512 threads (8 waves), 1 block/CU.
// Block = 64 batch rows x 128 cols; wave = 64 rows (4 m-frags) x 16 cols (distinct col-tile
// per wave -> per-CU weight stream 384 KB/cell, half of R4; each weight frag feeds 4 MFMAs).
// Quad (bid&~3 | 0..3) covers 512 cols of the same 64 rows; h exchanged via L3 mailbox ring.
// Own-column kk quad computed FIRST so flag-poll + sibling copy latency hides behind MFMA.
__global__ __launch_bounds__(512, 2) void gru_main(
    const float* __restrict__ x,
    const unsigned short* __restrict__ Wp,
    const unsigned short* __restrict__ Wip,
    const float* __restrict__ bih,
    const float* __restrict__ bhh,
    float* __restrict__ out,
    int* __restrict__ flags,
    unsigned int* __restrict__ xchg)
{
  __shared__ __align__(16) unsigned short hB[2][64 * HSTR];  // 137,216 B: bf16 h double buffer
  __shared__ __align__(16) unsigned short xpack[2][2048];    // x_t A-frags (4 m), t-parity

  const int tid  = threadIdx.x;
  const int wv   = tid >> 6;          // 0..7
  const int lane = tid & 63;
  const int l15  = lane & 15;
  const int l4   = lane >> 4;

  const int bid    = blockIdx.x;
  const int q      = bid & 3;          // col quadrant
  const int g      = bid >> 2;         // row group (0..63)
  const int b0r    = g * 64;
  const int sibase = bid & ~3;
  const int col    = q * 128 + wv * 16 + l15;   // global output column
  const int ntc    = q * 8 + wv;                // global 16-col tile (0..31)

  // weight fragment base pointers (per-layer strides applied in the loop)
  const unsigned short* wklB = Wp  + (size_t)ntc * 48 * 512 + (size_t)lane * 8;
  const unsigned short* wilB = Wip + (size_t)ntc * 3  * 512 + (size_t)lane * 8;

  for (int i = tid; i < 64 * HSTR; i += 512) hB[0][i] = 0;

  // stage x(t=0) into xpack[0]
#pragma unroll
  for (int e = 0; e < 4; ++e){
    int idx = e * 512 + tid;
    int m = idx >> 9, lw = (idx >> 3) & 63, j = idx & 7;
    float xv = (lw < 16) ? x[((size_t)(b0r + m * 16 + (lw & 15))) * (S_LEN * IN_D) + j] : 0.f;
    xpack[0][idx] = f2bf(xv);
  }
  __syncthreads();

  // fp32 h master in registers: [m][qq] -> row m*16+l4*4+qq, this lane's col
  float hreg[4][4];
#pragma unroll
  for (int m = 0; m < 4; ++m)
#pragma unroll
    for (int qq = 0; qq < 4; ++qq) hreg[m][qq] = 0.f;

  const int aof0 = (0 * 16 + l15) * HSTR + l4 * 8;
  const int aof1 = (1 * 16 + l15) * HSTR + l4 * 8;
  const int aof2 = (2 * 16 + l15) * HSTR + l4 * 8;
  const int aof3 = (3 * 16 + l15) * HSTR + l4 * 8;

  int cur = 0;
#pragma unroll 1
  for (int t = 0; t < S_LEN; ++t){
    const unsigned short* xp = &xpack[t & 1][0];
#pragma unroll 1
    for (int l = 0; l < NL; ++l){
      const int s    = t * NL + l;
      const int last = (s == S_LEN * NL - 1);
      const unsigned short* hbc = hB[cur];
      unsigned short*       hbn = hB[cur ^ 1];

      // biases (L2-hot)
      const float vR  = bih[l * 1536 + col]       + bhh[l * 1536 + col];
      const float vZ  = bih[l * 1536 + 512 + col] + bhh[l * 1536 + 512 + col];
      const float vNi = bih[l * 1536 + 1024 + col];
      const float vNh = bhh[l * 1536 + 1024 + col];
      f32x4 accR[4], accZ[4], accN[4], giN[4];
#pragma unroll
      for (int m = 0; m < 4; ++m){
        accR[m] = (f32x4){vR,vR,vR,vR};
        accZ[m] = (f32x4){vZ,vZ,vZ,vZ};
        accN[m] = (f32x4){vNh,vNh,vNh,vNh};
        giN[m]  = (f32x4){vNi,vNi,vNi,vNi};
      }

      // gi = x_t @ Wih^T (zero-padded K=8 fragments), 4 m-frags
      {
        const unsigned short* wil = wilB + (size_t)l * 32 * 3 * 512;
        short8 iR = *(const short8*)(wil);
        short8 iZ = *(const short8*)(wil + 512);
        short8 iN = *(const short8*)(wil + 1024);
#pragma unroll
        for (int m = 0; m < 4; ++m){
          short8 ax = *(const short8*)(xp + (m * 64 + lane) * 8);
          accR[m] = MFMA(ax, iR, accR[m]);
          accZ[m] = MFMA(ax, iZ, accZ[m]);
          giN[m]  = MFMA(ax, iN, giN[m]);
        }
      }

      const unsigned short* wkl = wklB + (size_t)l * 32 * 48 * 512;
#define DO_KK(kkv) { \
        const int kk_ = (kkv); \
        const unsigned short* w = wkl + (size_t)kk_ * 1536; \
        short8 bR = *(const short8*)(w); \
        short8 bZ = *(const short8*)(w + 512); \
        short8 bN = *(const short8*)(w + 1024); \
        const int ko = kk_ * 32; \
        short8 a0 = *(const short8*)(hbc + aof0 + ko); \
        short8 a1 = *(const short8*)(hbc + aof1 + ko); \
        short8 a2 = *(const short8*)(hbc + aof2 + ko); \
        short8 a3 = *(const short8*)(hbc + aof3 + ko); \
        accR[0] = MFMA(a0, bR, accR[0]); accZ[0] = MFMA(a0, bZ, accZ[0]); accN[0] = MFMA(a0, bN, accN[0]); \
        accR[1] = MFMA(a1, bR, accR[1]); accZ[1] = MFMA(a1, bZ, accZ[1]); accN[1] = MFMA(a1, bN, accN[1]); \
        accR[2] = MFMA(a2, bR, accR[2]); accZ[2] = MFMA(a2, bZ, accZ[2]); accN[2] = MFMA(a2, bN, accN[2]); \
        accR[3] = MFMA(a3, bR, accR[3]); accZ[3] = MFMA(a3, bZ, accZ[3]); accN[3] = MFMA(a3, bN, accN[3]); \
      }

      // phase A: own-column kk quad (h cols we wrote ourselves last stage)
#pragma unroll
      for (int kx = 0; kx < 4; ++kx) DO_KK(q * 4 + kx);

      // phase A2: poll sibling flags for h(s-1), copy their cols into hB[cur]
      if (s > 0){
        if (tid < 3){
          int sf = sibase | ((q + 1 + tid) & 3);
          while (__hip_atomic_load(&flags[sf], __ATOMIC_RELAXED, __HIP_MEMORY_SCOPE_AGENT) < s)
            __builtin_amdgcn_s_sleep(2);
        }
        __syncthreads();
        unsigned int* dst = (unsigned int*)hbc;
        const int slot = (s - 1) % RING;
#pragma unroll
        for (int j = 0; j < 3; ++j){
          const int qj = (q + 1 + j) & 3;
          const unsigned int* src = xchg + ((size_t)(sibase | qj) * RING + slot) * 4096;
#pragma unroll
          for (int k = 0; k < 8; ++k){
            int f = k * 512 + tid;
            unsigned v = __hip_atomic_load(src + f, __ATOMIC_RELAXED, __HIP_MEMORY_SCOPE_AGENT);
            dst[(f >> 6) * (HSTR / 2) + qj * 64 + (f & 63)] = v;
          }
        }
        __syncthreads();
      }

      // phase B: remaining 12 kk (sibling columns)
#pragma unroll
      for (int kx = 0; kx < 12; ++kx) DO_KK((q * 4 + 4 + kx) & 15);
#undef DO_KK

      // gates; write own cols to hB[cur^1] (LDS) + mailbox slot s%RING
      unsigned int* xob = xchg + ((size_t)bid * RING + s % RING) * 4096;
#pragma unroll
      for (int m = 0; m < 4; ++m){
#pragma unroll
        for (int qq = 0; qq < 4; ++qq){
          int b = m * 16 + l4 * 4 + qq;          // local batch row
          float r  = 1.f / (1.f + __expf(-accR[m][qq]));
          float z  = 1.f / (1.f + __expf(-accZ[m][qq]));
          float aN = giN[m][qq] + r * accN[m][qq];
          float n  = 1.f - 2.f / (1.f + __expf(2.f * aN));
          float hn = n + z * (hreg[m][qq] - n);  // (1-z)*n + z*h
          hreg[m][qq] = hn;
          unsigned bf = f2bf(hn);
          unsigned pb = (unsigned)__shfl_xor((int)bf, 1);
          if (!(l15 & 1)){
            unsigned pk = bf | (pb << 16);
            *(unsigned*)(hbn + b * HSTR + col) = pk;
            if (!last)
              __hip_atomic_store(xob + (b * 64 + wv * 8 + (l15 >> 1)), pk,
                                 __ATOMIC_RELAXED, __HIP_MEMORY_SCOPE_AGENT);
          }
        }
      }

      // stage x(t+1) before the end-of-stage barrier (visibility via B1)
      if (l == NL - 1 && t < S_LEN - 1){
#pragma unroll
        for (int e = 0; e < 4; ++e){
          int idx = e * 512 + tid;
          int m = idx >> 9, lw = (idx >> 3) & 63, j = idx & 7;
          float xv = (lw < 16) ? x[((size_t)(b0r + m * 16 + (lw & 15))) * (S_LEN * IN_D) + (size_t)(t + 1) * IN_D + j] : 0.f;
          xpack[(t + 1) & 1][idx] = f2bf(xv);
        }
      }

      if (!last){
        asm volatile("s_waitcnt vmcnt(0)" ::: "memory");   // drain this thread's mailbox stores
        __syncthreads();                                   // B1: all waves drained; LDS h complete
        if (tid == 0)
          __hip_atomic_store(&flags[bid], s + 1, __ATOMIC_RELAXED, __HIP_MEMORY_SCOPE_AGENT);
      }
      cur ^= 1;
    }
  }

  // epilogue: own 64r x 16c slice from registers
#pragma unroll
  for (int m = 0; m < 4; ++m)
#pragma unroll
    for (int qq = 0; qq < 4; ++qq){
      int b = m * 16 + l4 * 4 + qq;
      out[((size_t)(b0r + b)) * 512 + col] = hreg[m][qq];
    }
}

extern "C" void kernel_launch(void* const* d_in, const int* in_sizes, int n_in,
                              void* d_out, int out_size, void* d_ws, size_t ws_size,
                              hipStream_t stream){
  const float* x   = (const float*)d_in[0];
  const float* Wih = (const float*)d_in[1];
  const float* Whh = (const float*)d_in[2];
  const float* bih = (const float*)d_in[3];
  const float* bhh = (const float*)d_in[4];

  unsigned char* ws = (unsigned char*)d_ws;
  unsigned short* Wp   = (unsigned short*)(ws + OFF_WHH);
  unsigned short* Wip  = (unsigned short*)(ws + OFF_WIH);
  int*            flg  = (int*)(ws + OFF_FLAG);
  unsigned int*   xchg = (unsigned int*)(ws + OFF_XCHG);

  hipMemsetAsync(flg, 0, 256 * sizeof(int), stream);   // generation flags start at 0 every call
  prep_whh <<<1152, 256, 0, stream>>>(Whh, Wp);
  prep_wih <<<  72, 256, 0, stream>>>(Wih, Wip);
  gru_main <<< 256, 512, 0, stream>>>(x, Wp, Wip, bih, bhh, (float*)d_out, flg, xchg);
}

// Round 6
// 4619.540 us; speedup vs baseline: 1.3236x; 1.3236x over previous
//
#include <hip/hip_runtime.h>

typedef __attribute__((ext_vector_type(8))) short short8;
typedef __attribute__((ext_vector_type(4))) float f32x4;

#define MFMA(a,b,c) __builtin_amdgcn_mfma_f32_16x16x32_bf16(a,b,c,0,0,0)

// Problem dims
#define S_LEN 128
#define IN_D  8
#define HID   512
#define NL    3
#define HSTR  536       // bf16 h row stride (shorts)

// ws layout (bytes)
#define OFF_WHH  0                       // [3][32][16][3][64][8] bf16 = 4,718,592
#define OFF_WIH  (4718592)               // [3][32][3][64][8] bf16    =   294,912
#define OFF_FLAG (4718592 + 294912)      // 256 * int                 =     1,024
#define OFF_XCHG (OFF_FLAG + 1024)       // 256 blk * 2 slot * 16 KB  = 8,388,608

__device__ __forceinline__ unsigned short f2bf(float f){
  unsigned u = __float_as_uint(f);
  u += 0x7FFFu + ((u >> 16) & 1u);     // round-to-nearest-even
  return (unsigned short)(u >> 16);
}

// Pack Whh [3][1536][512] f32 -> bf16 B-fragments, gate-interleaved per kk:
// dst chunk gid = (((l*32+nt)*16+kk)*3+g)*64+lane ; holds Whh[l][g*512+nt*16+(lane&15)][kk*32+(lane>>4)*8+j]
__global__ void prep_whh(const float* __restrict__ Whh, unsigned short* __restrict__ Wp){
  int gid = blockIdx.x * 256 + threadIdx.x;     // 294912 total
  int lane = gid & 63;
  int r = gid >> 6;
  int g  = r % 3;  r /= 3;
  int kk = r & 15; r >>= 4;
  int nt = r & 31;
  int l  = r >> 5;
  int n  = g * 512 + nt * 16 + (lane & 15);
  int k0 = kk * 32 + (lane >> 4) * 8;
  const float* src = Whh + ((size_t)l * 1536 + n) * 512 + k0;
  unsigned short t[8];
#pragma unroll
  for (int j = 0; j < 8; ++j) t[j] = f2bf(src[j]);
  uint4 v;
  v.x = t[0] | ((unsigned)t[1] << 16);
  v.y = t[2] | ((unsigned)t[3] << 16);
  v.z = t[4] | ((unsigned)t[5] << 16);
  v.w = t[6] | ((unsigned)t[7] << 16);
  *(uint4*)(Wp + (size_t)gid * 8) = v;
}

// Pack Wih [3][1536][8] -> zero-padded (K=8 of 32) B-fragments, gate-interleaved:
// dst chunk gid = ((l*32+nt)*3+g)*64+lane
__global__ void prep_wih(const float* __restrict__ Wih, unsigned short* __restrict__ Wip){
  int gid = blockIdx.x * 256 + threadIdx.x;     // 18432 total
  int lane = gid & 63;
  int r = gid >> 6;
  int g  = r % 3;  r /= 3;
  int nt = r & 31;
  int l  = r >> 5;
  unsigned short t[8] = {0,0,0,0,0,0,0,0};
  if ((lane >> 4) == 0){
    int n = g * 512 + nt * 16 + (lane & 15);
    const float* src = Wih + ((size_t)l * 1536 + n) * 8;
#pragma unroll
    for (int j = 0; j < 8; ++j) t[j] = f2bf(src[j]);
  }
  uint4 v;
  v.x = t[0] | ((unsigned)t[1] << 16);
  v.y = t[2] | ((unsigned)t[3] << 16);
  v.z = t[4] | ((unsigned)t[5] << 16);
  v.w = t[6] | ((unsigned)t[7] << 16);
  *(uint4*)(Wip + (size_t)gid * 8) = v;
}

// Main: 256 blocks x 1024 threads (16 waves), 1 block/CU.
// Pair (bid, bid^4) shares batch rows [b0,b0+32); each computes 256 of 512 cols.
// half=(bid>>2)&1 -> per-XCD weight slice 2.36 MB, L2-resident (verified R4: FETCH=mailbox only).
// Step order: [poll partner flag + overlap 16KB UC mailbox copy] || [gi + own-half 8 kk]
//             -> barrier -> partner-half 8 kk -> gates -> stores -> vmcnt -> barrier -> flag.
// Own-half kk in [half*8, half*8+8) reads only h-cols this block wrote itself last step.
__global__ __launch_bounds__(1024) __attribute__((amdgpu_waves_per_eu(4, 4)))
void gru_main(
    const float* __restrict__ x,
    const unsigned short* __restrict__ Wp,
    const unsigned short* __restrict__ Wip,
    const float* __restrict__ bih,
    const float* __restrict__ bhh,
    float* __restrict__ out,
    int* __restrict__ flags,
    unsigned int* __restrict__ xchg)
{
  __shared__ __align__(16) unsigned short hB[2][32 * HSTR];  // bf16 h, double buffer
  __shared__ __align__(16) unsigned short xpack[2][1024];    // x_t A-frags, t-parity
  __shared__ float sBrz[3 * 1024];                           // bih+bhh (r,z)
  __shared__ float sBni[3 * 512];                            // bih (n)
  __shared__ float sBnh[3 * 512];                            // bhh (n)

  const int tid  = threadIdx.x;
  const int wv   = tid >> 6;
  const int lane = tid & 63;
  const int l15  = lane & 15;
  const int l4   = lane >> 4;

  const int bid     = blockIdx.x;
  const int bgroup  = ((bid >> 3) << 2) | (bid & 3);   // [0,128)
  const int half    = (bid >> 2) & 1;
  const int partner = bid ^ 4;
  const int b0      = bgroup * 32;
  const int cb      = half * 256 + wv * 16;            // this wave's column base
  const int ntc     = half * 16 + wv;                  // global 16-col tile index
  const int col     = cb + l15;
  const int pcb0    = (1 - half) * 256;                // partner's column base
  const int ko0     = half * 8;                        // own-half kk range start

  unsigned int* xown = xchg + (size_t)bid * 8192;      // 2 slots x 4096 u32

  for (int i = tid; i < 32 * HSTR; i += 1024){ hB[0][i] = 0; }
  for (int i = tid; i < 3072; i += 1024){
    int l = i >> 10, c = i & 1023;
    sBrz[i] = bih[l * 1536 + c] + bhh[l * 1536 + c];
  }
  for (int i = tid; i < 1536; i += 1024){
    int l = i >> 9, c = i & 511;
    sBni[i] = bih[l * 1536 + 1024 + c];
    sBnh[i] = bhh[l * 1536 + 1024 + c];
  }

  // fp32 h master in registers: [m][q] -> batch row m*16+l4*4+q, this lane's col
  float hreg[2][4];
#pragma unroll
  for (int m = 0; m < 2; ++m)
#pragma unroll
    for (int q = 0; q < 4; ++q) hreg[m][q] = 0.f;

  // xpack writer mapping: tid = (m*64+lane)*8 + j
  const int xm = tid >> 9, xl = (tid >> 3) & 63, xj = tid & 7;
  const size_t xbase = ((size_t)(b0 + xm * 16 + (xl & 15))) * (S_LEN * IN_D) + xj;
  const int xvalid = (xl < 16);
  { // stage x(t=0)
    float xv = xvalid ? x[xbase] : 0.f;
    xpack[0][tid] = f2bf(xv);
  }
  __syncthreads();

  const int aoff0 = l15 * HSTR + l4 * 8;          // A-frag m=0 (rows 0..15), shorts
  const int aoff1 = aoff0 + 16 * HSTR;            // A-frag m=1 (rows 16..31)

  const unsigned short* wklB = Wp  + (size_t)ntc * 48 * 512 + (size_t)lane * 8;
  const unsigned short* wilB = Wip + (size_t)ntc * 3  * 512 + (size_t)lane * 8;

  int cur = 0;
#pragma unroll 1
  for (int t = 0; t < S_LEN; ++t){
    const unsigned short* xp = &xpack[t & 1][0];
#pragma unroll 1
    for (int l = 0; l < NL; ++l){
      const int s    = t * NL + l;
      const int last = (s == S_LEN * NL - 1);
      const unsigned short* hbc = hB[cur];
      unsigned short*       hbw = hB[cur];         // mutable alias (partner-half copy dest)
      unsigned short*       hbn = hB[cur ^ 1];

      // ---- poll partner flag (set ~a full compute phase ago) + issue overlap copy ----
      if (s > 0){
        while (__hip_atomic_load(&flags[partner], __ATOMIC_RELAXED, __HIP_MEMORY_SCOPE_AGENT) < s)
          __builtin_amdgcn_s_sleep(4);
        const unsigned int* src = xchg + ((size_t)partner * 2 + ((s - 1) & 1)) * 4096;
#pragma unroll
        for (int e = 0; e < 4; ++e){
          int f = e * 1024 + tid;                  // u32 idx: row*128 + colpair
          unsigned v = __hip_atomic_load(src + f, __ATOMIC_RELAXED, __HIP_MEMORY_SCOPE_AGENT);
          int row = f >> 7, cp = f & 127;
          *(unsigned*)(hbw + row * HSTR + pcb0 + cp * 2) = v;
        }
      }

      // ---- biases from LDS ----
      const float vR  = sBrz[l * 1024 + col];
      const float vZ  = sBrz[l * 1024 + 512 + col];
      const float vNi = sBni[l * 512 + col];
      const float vNh = sBnh[l * 512 + col];
      f32x4 accR0 = {vR,vR,vR,vR},     accR1 = {vR,vR,vR,vR};
      f32x4 accZ0 = {vZ,vZ,vZ,vZ},     accZ1 = {vZ,vZ,vZ,vZ};
      f32x4 accN0 = {vNh,vNh,vNh,vNh}, accN1 = {vNh,vNh,vNh,vNh};
      f32x4 giN0  = {vNi,vNi,vNi,vNi}, giN1  = {vNi,vNi,vNi,vNi};

      // ---- gi = x_t @ Wih^T (zero-padded K=8 fragments) ----
      {
        short8 ax0 = *(const short8*)(xp + lane * 8);
        short8 ax1 = *(const short8*)(xp + 512 + lane * 8);
        const unsigned short* wil = wilB + (size_t)l * (32 * 3 * 512);
        short8 iR = *(const short8*)(wil);
        short8 iZ = *(const short8*)(wil + 512);
        short8 iN = *(const short8*)(wil + 1024);
        accR0 = MFMA(ax0, iR, accR0);  accR1 = MFMA(ax1, iR, accR1);
        accZ0 = MFMA(ax0, iZ, accZ0);  accZ1 = MFMA(ax1, iZ, accZ1);
        giN0  = MFMA(ax0, iN, giN0);   giN1  = MFMA(ax1, iN, giN1);
      }

      const unsigned short* wkl = wklB + (size_t)l * (32 * 48 * 512);
#define DO_KK(kkv) { \
        const int kk_ = (kkv); \
        const unsigned short* w = wkl + kk_ * 1536; \
        short8 bR = *(const short8*)(w); \
        short8 bZ = *(const short8*)(w + 512); \
        short8 bN = *(const short8*)(w + 1024); \
        short8 a0 = *(const short8*)(hbc + aoff0 + kk_ * 32); \
        short8 a1 = *(const short8*)(hbc + aoff1 + kk_ * 32); \
        accR0 = MFMA(a0, bR, accR0);  accR1 = MFMA(a1, bR, accR1); \
        accZ0 = MFMA(a0, bZ, accZ0);  accZ1 = MFMA(a1, bZ, accZ1); \
        accN0 = MFMA(a0, bN, accN0);  accN1 = MFMA(a1, bN, accN1); \
      }

      // ---- own-half kk (reads only cols this block wrote last step) ----
#pragma unroll
      for (int kx = 0; kx < 8; ++kx) DO_KK(ko0 + kx);

      __syncthreads();   // partner-half copy (all waves) visible

      // ---- partner-half kk ----
#pragma unroll
      for (int kx = 0; kx < 8; ++kx) DO_KK((8 - ko0) + kx);
#undef DO_KK

      // ---- gates; write own half to hB[cur^1] + mailbox slot s&1 ----
      unsigned int* xob = xown + (s & 1) * 4096;
#pragma unroll
      for (int m = 0; m < 2; ++m){
        f32x4 aR  = m ? accR1 : accR0;
        f32x4 aZ  = m ? accZ1 : accZ0;
        f32x4 aN4 = m ? accN1 : accN0;
        f32x4 gN  = m ? giN1  : giN0;
#pragma unroll
        for (int q = 0; q < 4; ++q){
          int b = m * 16 + l4 * 4 + q;           // batch row within tile
          float r  = 1.f / (1.f + __expf(-aR[q]));
          float z  = 1.f / (1.f + __expf(-aZ[q]));
          float aN = gN[q] + r * aN4[q];
          float n  = 1.f - 2.f / (1.f + __expf(2.f * aN));
          float hn = n + z * (hreg[m][q] - n);   // (1-z)*n + z*h
          hreg[m][q] = hn;
          unsigned bf = f2bf(hn);
          unsigned pb = (unsigned)__shfl_xor((int)bf, 1);
          if (!(l15 & 1)){
            unsigned pk = bf | (pb << 16);
            *(unsigned*)(hbn + b * HSTR + col) = pk;
            if (!last)
              __hip_atomic_store(xob + (b * 128 + wv * 8 + (l15 >> 1)), pk,
                                 __ATOMIC_RELAXED, __HIP_MEMORY_SCOPE_AGENT);
          }
        }
      }

      // stage x(t+1) before the end-of-step barrier
      if (l == NL - 1 && t < S_LEN - 1){
        float xv = xvalid ? x[xbase + (size_t)(t + 1) * IN_D] : 0.f;
        xpack[(t + 1) & 1][tid] = f2bf(xv);
      }

      if (!last){
        asm volatile("s_waitcnt vmcnt(0)" ::: "memory");   // mailbox stores drained
        __syncthreads();
        if (tid == 0)
          __hip_atomic_store(&flags[bid], s + 1, __ATOMIC_RELAXED, __HIP_MEMORY_SCOPE_AGENT);
      }
      cur ^= 1;
    }
  }

  // epilogue: own 32r x 16c slice from registers
#pragma unroll
  for (int m = 0; m < 2; ++m)
#pragma unroll
    for (int q = 0; q < 4; ++q){
      int b = m * 16 + l4 * 4 + q;
      out[((size_t)(b0 + b)) * 512 + col] = hreg[m][q];
    }
}

extern "C" void kernel_launch(void* const* d_in, const int* in_sizes, int n_in,
                              void* d_out, int out_size, void* d_ws, size_t ws_size,
                              hipStream_t stream){
  const float* x   = (const float*)d_in[0];
  const float* Wih = (const float*)d_in[1];
  const float* Whh = (const float*)d_in[2];
  const float* bih = (const float*)d_in[3];
  const float* bhh = (const float*)d_in[4];

  unsigned char* ws = (unsigned char*)d_ws;
  unsigned short* Wp   = (unsigned short*)(ws + OFF_WHH);
  unsigned short* Wip  = (unsigned short*)(ws + OFF_WIH);
  int*            flg  = (int*)(ws + OFF_FLAG);
  unsigned int*   xchg = (unsigned int*)(ws + OFF_XCHG);

  hipMemsetAsync(flg, 0, 256 * sizeof(int), stream);   // generation flags start at 0 every call
  prep_whh <<<1152, 256, 0, stream>>>(Whh, Wp);
  prep_wih <<<  72, 256, 0, stream>>>(Wih, Wip);
  gru_main <<< 256, 1024, 0, stream>>>(x, Wp, Wip, bih, bhh, (float*)d_out, flg, xchg);
}